// Round 1
// baseline (274.837 us; speedup 1.0000x reference)
//
#include <hip/hip_runtime.h>
#include <hip/hip_bf16.h>

#define T_PER_BLK 8
#define EPS_F 1e-5f

static __device__ __forceinline__ unsigned int pack_bf16x2(float a, float b) {
    union { float f; unsigned int u; } ca, cb;
    ca.f = a; cb.f = b;
    unsigned int ua = (ca.u + 0x7fffu + ((ca.u >> 16) & 1u)) >> 16;
    unsigned int ub = (cb.u + 0x7fffu + ((cb.u >> 16) & 1u)) >> 16;
    return ua | (ub << 16);
}

__global__ __launch_bounds__(256, 2)
void fused_stream_mix(const float* __restrict__ streams,
                      const float* __restrict__ norm_scale,
                      const float* __restrict__ proj_w,
                      const float* __restrict__ proj_b,
                      const float* __restrict__ out_scale,
                      float* __restrict__ out)
{
    __shared__ unsigned int xs[T_PER_BLK][2048];   // 8 tokens x 4096 bf16 (packed x2) = 64 KB
    __shared__ float raw_lds[T_PER_BLK][52];       // 48 logits, padded
    __shared__ float Mm_lds[T_PER_BLK][16];        // per-token 4x4 combine matrix
    __shared__ float invr[T_PER_BLK];

    const int tid  = threadIdx.x;
    const int wv   = tid >> 6;
    const int lane = tid & 63;
    const size_t tok0 = (size_t)blockIdx.x * T_PER_BLK;

    // ---------- Phase 1: load streams -> LDS bf16, compute inv RMS ----------
    #pragma unroll
    for (int tt = 0; tt < 2; ++tt) {
        const int t = wv * 2 + tt;
        const float* src = streams + (tok0 + t) * 4096;
        float ssq = 0.f;
        #pragma unroll
        for (int j = 0; j < 16; ++j) {
            float4 v = *reinterpret_cast<const float4*>(src + j * 256 + lane * 4);
            ssq = fmaf(v.x, v.x, ssq); ssq = fmaf(v.y, v.y, ssq);
            ssq = fmaf(v.z, v.z, ssq); ssq = fmaf(v.w, v.w, ssq);
            const int di = j * 128 + lane * 2;
            xs[t][di]     = pack_bf16x2(v.x, v.y);
            xs[t][di + 1] = pack_bf16x2(v.z, v.w);
        }
        #pragma unroll
        for (int m = 32; m >= 1; m >>= 1) ssq += __shfl_xor(ssq, m, 64);
        if (lane == 0) invr[t] = rsqrtf(ssq * (1.f / 4096.f) + EPS_F);
    }
    __syncthreads();

    // ---------- Phase 2: projection. wave wv owns logit rows [12*wv, 12*wv+12) ----------
    const int k0 = wv * 12;
    float acc[T_PER_BLK][12];
    #pragma unroll
    for (int t = 0; t < T_PER_BLK; ++t)
        #pragma unroll
        for (int kk = 0; kk < 12; ++kk) acc[t][kk] = 0.f;

    for (int j = 0; j < 32; ++j) {
        const int cp = j * 64 + lane;   // column-pair index 0..2047
        const float2 ns = *reinterpret_cast<const float2*>(norm_scale + 2 * cp);
        float wlo[12], whi[12];
        #pragma unroll
        for (int kk = 0; kk < 12; ++kk) {
            const float2 wvv = *reinterpret_cast<const float2*>(
                proj_w + (size_t)(k0 + kk) * 4096 + 2 * cp);
            wlo[kk] = wvv.x * ns.x;
            whi[kk] = wvv.y * ns.y;
        }
        #pragma unroll
        for (int t = 0; t < T_PER_BLK; ++t) {
            const unsigned int u = xs[t][cp];
            const float xlo = __uint_as_float(u << 16);
            const float xhi = __uint_as_float(u & 0xffff0000u);
            #pragma unroll
            for (int kk = 0; kk < 12; ++kk) {
                acc[t][kk] = fmaf(xlo, wlo[kk], acc[t][kk]);
                acc[t][kk] = fmaf(xhi, whi[kk], acc[t][kk]);
            }
        }
    }

    // reduce across the wave, scale by inv_rms, add bias
    #pragma unroll
    for (int t = 0; t < T_PER_BLK; ++t) {
        #pragma unroll
        for (int kk = 0; kk < 12; ++kk) {
            float v = acc[t][kk];
            #pragma unroll
            for (int m = 32; m >= 1; m >>= 1) v += __shfl_xor(v, m, 64);
            if (lane == 0) raw_lds[t][k0 + kk] = v * invr[t] + proj_b[k0 + kk];
        }
    }
    __syncthreads();

    // ---------- Phase 3: per-token 4x4 math (one thread per token) ----------
    if (tid < T_PER_BLK) {
        const int t = tid;
        float A[16], Bm[16], Cc[16];
        #pragma unroll
        for (int i = 0; i < 16; ++i) {
            A[i]  = raw_lds[t][i];
            Bm[i] = raw_lds[t][16 + i];
            Cc[i] = raw_lds[t][32 + i];
        }
        // H_pre: row softmax -> c[j] = 0.25 * column sums
        float c[4] = {0.f, 0.f, 0.f, 0.f};
        #pragma unroll
        for (int i = 0; i < 4; ++i) {
            const float m = fmaxf(fmaxf(A[i*4+0], A[i*4+1]), fmaxf(A[i*4+2], A[i*4+3]));
            const float e0 = expf(A[i*4+0] - m), e1 = expf(A[i*4+1] - m);
            const float e2 = expf(A[i*4+2] - m), e3 = expf(A[i*4+3] - m);
            const float inv = 1.f / (e0 + e1 + e2 + e3);
            c[0] = fmaf(e0, inv, c[0]); c[1] = fmaf(e1, inv, c[1]);
            c[2] = fmaf(e2, inv, c[2]); c[3] = fmaf(e3, inv, c[3]);
        }
        c[0] *= 0.25f; c[1] *= 0.25f; c[2] *= 0.25f; c[3] *= 0.25f;

        // H_post: column softmax -> rs[i] = row sums
        float rs[4] = {0.f, 0.f, 0.f, 0.f};
        #pragma unroll
        for (int j = 0; j < 4; ++j) {
            const float m = fmaxf(fmaxf(Bm[j], Bm[4+j]), fmaxf(Bm[8+j], Bm[12+j]));
            const float e0 = expf(Bm[j] - m),   e1 = expf(Bm[4+j] - m);
            const float e2 = expf(Bm[8+j] - m), e3 = expf(Bm[12+j] - m);
            const float inv = 1.f / (e0 + e1 + e2 + e3);
            rs[0] = fmaf(e0, inv, rs[0]); rs[1] = fmaf(e1, inv, rs[1]);
            rs[2] = fmaf(e2, inv, rs[2]); rs[3] = fmaf(e3, inv, rs[3]);
        }

        // Cayley iterative
        float W[16], Y[16];
        #pragma unroll
        for (int i = 0; i < 4; ++i)
            #pragma unroll
            for (int j = 0; j < 4; ++j)
                W[i*4+j] = Cc[i*4+j] - Cc[j*4+i];
        #pragma unroll
        for (int i = 0; i < 16; ++i) Y[i] = 0.1f * W[i];
        Y[0] += 1.f; Y[5] += 1.f; Y[10] += 1.f; Y[15] += 1.f;
        #pragma unroll
        for (int it = 0; it < 2; ++it) {
            float T1[16];
            #pragma unroll
            for (int i = 0; i < 16; ++i) T1[i] = Y[i];
            T1[0] += 1.f; T1[5] += 1.f; T1[10] += 1.f; T1[15] += 1.f;
            float Yn[16];
            #pragma unroll
            for (int i = 0; i < 4; ++i)
                #pragma unroll
                for (int j = 0; j < 4; ++j) {
                    float s = W[i*4+0] * T1[0*4+j];
                    s = fmaf(W[i*4+1], T1[1*4+j], s);
                    s = fmaf(W[i*4+2], T1[2*4+j], s);
                    s = fmaf(W[i*4+3], T1[3*4+j], s);
                    Yn[i*4+j] = ((i == j) ? 1.f : 0.f) + 0.05f * s;
                }
            #pragma unroll
            for (int i = 0; i < 16; ++i) Y[i] = Yn[i];
        }

        const float os = out_scale[0];
        #pragma unroll
        for (int i = 0; i < 4; ++i)
            #pragma unroll
            for (int j = 0; j < 4; ++j)
                Mm_lds[t][i*4+j] = Y[i*4+j] + os * rs[i] * c[j];
    }
    __syncthreads();

    // ---------- Phase 4: out = M @ streams (from LDS bf16) ----------
    #pragma unroll
    for (int tt = 0; tt < 2; ++tt) {
        const int t = wv * 2 + tt;
        float Mr[16];
        #pragma unroll
        for (int i = 0; i < 16; ++i) Mr[i] = Mm_lds[t][i];
        float* dst = out + (tok0 + t) * 4096;
        #pragma unroll
        for (int p = 0; p < 8; ++p) {
            const int cp = p * 64 + lane;   // column-pair 0..511 within a d-row
            float xl[4], xh[4];
            #pragma unroll
            for (int jr = 0; jr < 4; ++jr) {
                const unsigned int u = xs[t][jr * 512 + cp];
                xl[jr] = __uint_as_float(u << 16);
                xh[jr] = __uint_as_float(u & 0xffff0000u);
            }
            #pragma unroll
            for (int i = 0; i < 4; ++i) {
                float o0 = Mr[i*4+0] * xl[0];
                o0 = fmaf(Mr[i*4+1], xl[1], o0);
                o0 = fmaf(Mr[i*4+2], xl[2], o0);
                o0 = fmaf(Mr[i*4+3], xl[3], o0);
                float o1 = Mr[i*4+0] * xh[0];
                o1 = fmaf(Mr[i*4+1], xh[1], o1);
                o1 = fmaf(Mr[i*4+2], xh[2], o1);
                o1 = fmaf(Mr[i*4+3], xh[3], o1);
                *reinterpret_cast<float2*>(dst + i * 1024 + 2 * cp) = make_float2(o0, o1);
            }
        }
    }
}

extern "C" void kernel_launch(void* const* d_in, const int* in_sizes, int n_in,
                              void* d_out, int out_size, void* d_ws, size_t ws_size,
                              hipStream_t stream) {
    const float* streams    = (const float*)d_in[0];
    const float* norm_scale = (const float*)d_in[1];
    const float* proj_w     = (const float*)d_in[2];
    const float* proj_b     = (const float*)d_in[3];
    const float* out_scale  = (const float*)d_in[4];
    float* outp = (float*)d_out;

    const int n_tok = in_sizes[0] / 4096;          // B*S = 16384
    dim3 grid(n_tok / T_PER_BLK);                  // 2048 blocks
    fused_stream_mix<<<grid, 256, 0, stream>>>(streams, norm_scale, proj_w,
                                               proj_b, out_scale, outp);
}

// Round 2
// 185.889 us; speedup vs baseline: 1.4785x; 1.4785x over previous
//
#include <hip/hip_runtime.h>
#include <hip/hip_bf16.h>

#define T_PER_BLK 8
#define EPS_F 1e-5f

typedef __bf16 bf16x8 __attribute__((ext_vector_type(8)));
typedef float f32x4 __attribute__((ext_vector_type(4)));

static __device__ __forceinline__ unsigned int pack_bf16x2(float a, float b) {
    union { float f; unsigned int u; } ca, cb;
    ca.f = a; cb.f = b;
    unsigned int ua = (ca.u + 0x7fffu + ((ca.u >> 16) & 1u)) >> 16;
    unsigned int ub = (cb.u + 0x7fffu + ((cb.u >> 16) & 1u)) >> 16;
    return ua | (ub << 16);
}

// ---- setup: wbf[n][k] = bf16(proj_w[n][k] * norm_scale[k]), [48][4096] ----
__global__ void scale_weights(const float* __restrict__ w,
                              const float* __restrict__ ns,
                              unsigned int* __restrict__ wbf)
{
    const int i = (blockIdx.x * 256 + threadIdx.x) * 4;   // element index, 4 at a time
    const float4 wv = *reinterpret_cast<const float4*>(w + i);
    const float4 nv = *reinterpret_cast<const float4*>(ns + (i & 4095));
    uint2 o;
    o.x = pack_bf16x2(wv.x * nv.x, wv.y * nv.y);
    o.y = pack_bf16x2(wv.z * nv.z, wv.w * nv.w);
    *reinterpret_cast<uint2*>(wbf + (i >> 1)) = o;
}

__global__ __launch_bounds__(256, 2)
void fused_stream_mix(const float* __restrict__ streams,
                      const unsigned short* __restrict__ wbf,   // scaled bf16 weights [48][4096]
                      const float* __restrict__ proj_b,
                      const float* __restrict__ out_scale,
                      float* __restrict__ out)
{
    __shared__ unsigned int xs[T_PER_BLK][2048];   // 8 tokens x 4096 bf16 packed = 64 KB
    __shared__ float red[4][3][32][4];             // split-K partial D tiles (valid lanes 0..31)
    __shared__ float raw_lds[T_PER_BLK][48];
    __shared__ float Mm_lds[T_PER_BLK][16];
    __shared__ float invr[T_PER_BLK];

    const int tid  = threadIdx.x;
    const int wv   = tid >> 6;
    const int lane = tid & 63;
    const size_t tok0 = (size_t)blockIdx.x * T_PER_BLK;

    // ---------- Phase 1: streams -> LDS bf16, inv RMS ----------
    #pragma unroll
    for (int tt = 0; tt < 2; ++tt) {
        const int t = wv * 2 + tt;
        const float* src = streams + (tok0 + t) * 4096;
        float ssq = 0.f;
        #pragma unroll
        for (int j = 0; j < 16; ++j) {
            float4 v = *reinterpret_cast<const float4*>(src + j * 256 + lane * 4);
            ssq = fmaf(v.x, v.x, ssq); ssq = fmaf(v.y, v.y, ssq);
            ssq = fmaf(v.z, v.z, ssq); ssq = fmaf(v.w, v.w, ssq);
            const int di = j * 128 + lane * 2;
            xs[t][di]     = pack_bf16x2(v.x, v.y);
            xs[t][di + 1] = pack_bf16x2(v.z, v.w);
        }
        #pragma unroll
        for (int m = 32; m >= 1; m >>= 1) ssq += __shfl_xor(ssq, m, 64);
        if (lane == 0) invr[t] = rsqrtf(ssq * (1.f / 4096.f) + EPS_F);
    }
    __syncthreads();

    // ---------- Phase 2: MFMA projection, split-K across waves ----------
    {
        const int arow = lane & 7;                 // token row (duplicated into rows 8..15)
        const int koff = (lane >> 4) * 8;          // k sub-offset within 32-wide K-step
        const int bcol = lane & 15;                // output column within a 16-wide N-tile
        const int kbase = wv * 1024;               // this wave's K quarter

        const unsigned int* xrow = &xs[arow][0];
        const unsigned short* wp = wbf + (size_t)bcol * 4096 + kbase + koff;

        f32x4 acc0 = {0.f, 0.f, 0.f, 0.f};
        f32x4 acc1 = acc0, acc2 = acc0;

        #pragma unroll 4
        for (int ks = 0; ks < 32; ++ks) {
            const int k = kbase + ks * 32 + koff;
            bf16x8 a  = *reinterpret_cast<const bf16x8*>(&xrow[k >> 1]);
            bf16x8 b0 = *reinterpret_cast<const bf16x8*>(wp + ks * 32);
            bf16x8 b1 = *reinterpret_cast<const bf16x8*>(wp + 16 * 4096 + ks * 32);
            bf16x8 b2 = *reinterpret_cast<const bf16x8*>(wp + 32 * 4096 + ks * 32);
            acc0 = __builtin_amdgcn_mfma_f32_16x16x32_bf16(a, b0, acc0, 0, 0, 0);
            acc1 = __builtin_amdgcn_mfma_f32_16x16x32_bf16(a, b1, acc1, 0, 0, 0);
            acc2 = __builtin_amdgcn_mfma_f32_16x16x32_bf16(a, b2, acc2, 0, 0, 0);
        }
        if (lane < 32) {   // rows 0..7 of D live in lanes 0..31
            #pragma unroll
            for (int r = 0; r < 4; ++r) {
                red[wv][0][lane][r] = acc0[r];
                red[wv][1][lane][r] = acc1[r];
                red[wv][2][lane][r] = acc2[r];
            }
        }
    }
    __syncthreads();

    // cross-wave K reduction: 8 tok x 48 n = 384 values
    for (int idx = tid; idx < 384; idx += 256) {
        const int t = idx & 7, n = idx >> 3;
        const int tile = n >> 4, col = n & 15;
        const int lsrc = ((t >> 2) << 4) | col;    // D layout: row=(lane>>4)*4+reg
        const int reg  = t & 3;
        float s = red[0][tile][lsrc][reg] + red[1][tile][lsrc][reg]
                + red[2][tile][lsrc][reg] + red[3][tile][lsrc][reg];
        raw_lds[t][n] = s * invr[t] + proj_b[n];
    }
    __syncthreads();

    // ---------- Phase 3: per-token 4x4 math ----------
    if (tid < T_PER_BLK) {
        const int t = tid;
        float A[16], Bm[16], Cc[16];
        #pragma unroll
        for (int i = 0; i < 16; ++i) {
            A[i]  = raw_lds[t][i];
            Bm[i] = raw_lds[t][16 + i];
            Cc[i] = raw_lds[t][32 + i];
        }
        float c[4] = {0.f, 0.f, 0.f, 0.f};
        #pragma unroll
        for (int i = 0; i < 4; ++i) {
            const float m = fmaxf(fmaxf(A[i*4+0], A[i*4+1]), fmaxf(A[i*4+2], A[i*4+3]));
            const float e0 = expf(A[i*4+0] - m), e1 = expf(A[i*4+1] - m);
            const float e2 = expf(A[i*4+2] - m), e3 = expf(A[i*4+3] - m);
            const float inv = 1.f / (e0 + e1 + e2 + e3);
            c[0] = fmaf(e0, inv, c[0]); c[1] = fmaf(e1, inv, c[1]);
            c[2] = fmaf(e2, inv, c[2]); c[3] = fmaf(e3, inv, c[3]);
        }
        c[0] *= 0.25f; c[1] *= 0.25f; c[2] *= 0.25f; c[3] *= 0.25f;

        float rs[4] = {0.f, 0.f, 0.f, 0.f};
        #pragma unroll
        for (int j = 0; j < 4; ++j) {
            const float m = fmaxf(fmaxf(Bm[j], Bm[4+j]), fmaxf(Bm[8+j], Bm[12+j]));
            const float e0 = expf(Bm[j] - m),   e1 = expf(Bm[4+j] - m);
            const float e2 = expf(Bm[8+j] - m), e3 = expf(Bm[12+j] - m);
            const float inv = 1.f / (e0 + e1 + e2 + e3);
            rs[0] = fmaf(e0, inv, rs[0]); rs[1] = fmaf(e1, inv, rs[1]);
            rs[2] = fmaf(e2, inv, rs[2]); rs[3] = fmaf(e3, inv, rs[3]);
        }

        float W[16], Y[16];
        #pragma unroll
        for (int i = 0; i < 4; ++i)
            #pragma unroll
            for (int j = 0; j < 4; ++j)
                W[i*4+j] = Cc[i*4+j] - Cc[j*4+i];
        #pragma unroll
        for (int i = 0; i < 16; ++i) Y[i] = 0.1f * W[i];
        Y[0] += 1.f; Y[5] += 1.f; Y[10] += 1.f; Y[15] += 1.f;
        #pragma unroll
        for (int it = 0; it < 2; ++it) {
            float T1[16];
            #pragma unroll
            for (int i = 0; i < 16; ++i) T1[i] = Y[i];
            T1[0] += 1.f; T1[5] += 1.f; T1[10] += 1.f; T1[15] += 1.f;
            float Yn[16];
            #pragma unroll
            for (int i = 0; i < 4; ++i)
                #pragma unroll
                for (int j = 0; j < 4; ++j) {
                    float s = W[i*4+0] * T1[0*4+j];
                    s = fmaf(W[i*4+1], T1[1*4+j], s);
                    s = fmaf(W[i*4+2], T1[2*4+j], s);
                    s = fmaf(W[i*4+3], T1[3*4+j], s);
                    Yn[i*4+j] = ((i == j) ? 1.f : 0.f) + 0.05f * s;
                }
            #pragma unroll
            for (int i = 0; i < 16; ++i) Y[i] = Yn[i];
        }

        const float os = out_scale[0];
        #pragma unroll
        for (int i = 0; i < 4; ++i)
            #pragma unroll
            for (int j = 0; j < 4; ++j)
                Mm_lds[t][i*4+j] = Y[i*4+j] + os * rs[i] * c[j];
    }
    __syncthreads();

    // ---------- Phase 4: out = M @ streams, float4 stores ----------
    #pragma unroll
    for (int tt = 0; tt < 2; ++tt) {
        const int t = wv * 2 + tt;
        float Mr[16];
        #pragma unroll
        for (int i = 0; i < 16; ++i) Mr[i] = Mm_lds[t][i];
        float* dst = out + (tok0 + t) * 4096;
        #pragma unroll
        for (int it = 0; it < 4; ++it) {
            const int cq = it * 64 + lane;     // quad-of-columns index 0..255
            float x[4][4];
            #pragma unroll
            for (int j = 0; j < 4; ++j) {
                const uint2 u = *reinterpret_cast<const uint2*>(&xs[t][j * 512 + cq * 2]);
                x[j][0] = __uint_as_float(u.x << 16);
                x[j][1] = __uint_as_float(u.x & 0xffff0000u);
                x[j][2] = __uint_as_float(u.y << 16);
                x[j][3] = __uint_as_float(u.y & 0xffff0000u);
            }
            #pragma unroll
            for (int i = 0; i < 4; ++i) {
                float4 o;
                o.x = Mr[i*4+0]*x[0][0]; o.y = Mr[i*4+0]*x[0][1];
                o.z = Mr[i*4+0]*x[0][2]; o.w = Mr[i*4+0]*x[0][3];
                #pragma unroll
                for (int j = 1; j < 4; ++j) {
                    o.x = fmaf(Mr[i*4+j], x[j][0], o.x);
                    o.y = fmaf(Mr[i*4+j], x[j][1], o.y);
                    o.z = fmaf(Mr[i*4+j], x[j][2], o.z);
                    o.w = fmaf(Mr[i*4+j], x[j][3], o.w);
                }
                *reinterpret_cast<float4*>(dst + i * 1024 + cq * 4) = o;
            }
        }
    }
}

extern "C" void kernel_launch(void* const* d_in, const int* in_sizes, int n_in,
                              void* d_out, int out_size, void* d_ws, size_t ws_size,
                              hipStream_t stream) {
    const float* streams    = (const float*)d_in[0];
    const float* norm_scale = (const float*)d_in[1];
    const float* proj_w     = (const float*)d_in[2];
    const float* proj_b     = (const float*)d_in[3];
    const float* out_scale  = (const float*)d_in[4];
    float* outp = (float*)d_out;

    unsigned int* wbf = (unsigned int*)d_ws;       // 48*4096 bf16 = 393216 B

    // fold norm_scale into weights, cast to bf16
    scale_weights<<<dim3(192), 256, 0, stream>>>(proj_w, norm_scale, wbf);

    const int n_tok = in_sizes[0] / 4096;          // B*S = 16384
    dim3 grid(n_tok / T_PER_BLK);                  // 2048 blocks
    fused_stream_mix<<<grid, 256, 0, stream>>>(streams,
                                               (const unsigned short*)wbf,
                                               proj_b, out_scale, outp);
}